// Round 9
// baseline (91.294 us; speedup 1.0000x reference)
//
#include <hip/hip_runtime.h>
#include <hip/hip_bf16.h>

typedef __bf16 bf16x8 __attribute__((ext_vector_type(8)));
typedef __bf16 bf16x4 __attribute__((ext_vector_type(4)));
typedef float  floatx4 __attribute__((ext_vector_type(4)));

#define SD 4096
#define DH 64
#define NB 4

__device__ __forceinline__ float exp2fast(float x) { return __builtin_amdgcn_exp2f(x); }

__device__ __forceinline__ unsigned pack_bf16_2(float a, float b) {
    union { __bf16 h[2]; unsigned u; } cvt;
    cvt.h[0] = (__bf16)a; cvt.h[1] = (__bf16)b;
    return cvt.u;
}

// Full drain + barrier (raw; compiler doesn't add extra waits around it).
__device__ __forceinline__ void sync_all() {
    asm volatile("s_waitcnt vmcnt(0) lgkmcnt(0)\n\ts_barrier" ::: "memory");
}

// Direct global->LDS DMA, 16 B per lane. LDS dest must be wave-uniform;
// HW writes dest + lane*16.
__device__ __forceinline__ void load_lds16(const void* g, void* l) {
    __builtin_amdgcn_global_load_lds(
        (const __attribute__((address_space(1))) unsigned int*)g,
        (__attribute__((address_space(3))) unsigned int*)l, 16, 0, 0);
}

// chunk index g (16B units within an 8KB tile) -> swizzled element offset
__device__ __forceinline__ int swz8(int g) {
    int row = g >> 3, ch = g & 7;
    return row * 64 + ((ch ^ (row & 7)) << 3);
}

// Pre-pass: build per-64-key-tile LDS images (8 KB each, XOR-swizzled chunk
// order) for K (bf16 natural rows) and V (transposed + column-PERMUTED so
// P^T exits QK^T already in B-operand order).
__global__ __launch_bounds__(256) void prep_kernel(const float* __restrict__ k,
                                                   const float* __restrict__ v,
                                                   __bf16* __restrict__ kbs,
                                                   __bf16* __restrict__ vts) {
    __shared__ __bf16 tile[64][72];   // [d][key]
    const int bid = blockIdx.x;       // b*64 + kt
    const int tid = threadIdx.x;
    const long base = (long)bid * 4096;   // element offset of 64x64 fp32 tile

    // ---- K: convert + swizzled chunk write (no LDS round-trip) ----
    {
        const float* src = k + base + tid * 16;   // = row(t>>2)*64 + (t&3)*16
        float4 f0 = *(const float4*)(src);
        float4 f1 = *(const float4*)(src + 4);
        float4 f2 = *(const float4*)(src + 8);
        float4 f3 = *(const float4*)(src + 12);
        bf16x8 c0, c1;
        c0[0]=(__bf16)f0.x; c0[1]=(__bf16)f0.y; c0[2]=(__bf16)f0.z; c0[3]=(__bf16)f0.w;
        c0[4]=(__bf16)f1.x; c0[5]=(__bf16)f1.y; c0[6]=(__bf16)f1.z; c0[7]=(__bf16)f1.w;
        c1[0]=(__bf16)f2.x; c1[1]=(__bf16)f2.y; c1[2]=(__bf16)f2.z; c1[3]=(__bf16)f2.w;
        c1[4]=(__bf16)f3.x; c1[5]=(__bf16)f3.y; c1[6]=(__bf16)f3.z; c1[7]=(__bf16)f3.w;
        __bf16* dst = kbs + base;   // 4096 bf16 elements per tile
        *(bf16x8*)(dst + swz8(tid * 2))     = c0;
        *(bf16x8*)(dst + swz8(tid * 2 + 1)) = c1;
    }
    // ---- V: load 64x64, transpose into tile[d][key] ----
    {
        int r = tid >> 2, ds0 = (tid & 3) * 16;
#pragma unroll
        for (int i = 0; i < 4; ++i) {
            float4 f = *(const float4*)(v + base + r * 64 + ds0 + i * 4);
            tile[ds0 + i*4 + 0][r] = (__bf16)f.x;
            tile[ds0 + i*4 + 1][r] = (__bf16)f.y;
            tile[ds0 + i*4 + 2][r] = (__bf16)f.z;
            tile[ds0 + i*4 + 3][r] = (__bf16)f.w;
        }
    }
    __syncthreads();
    // ---- V: permuted-column chunk write (swizzled positions) ----
    {
        __bf16* dst = vts + base;
#pragma unroll
        for (int h = 0; h < 2; ++h) {
            int qc = tid * 2 + h;
            int d = qc >> 3, c8 = (qc & 7) * 8;
            bf16x8 o;
#pragma unroll
            for (int i = 0; i < 8; ++i) {
                int col = c8 + i;
                int key = ((col >> 5) * 2 + ((col >> 2) & 1)) * 16
                        + ((col >> 3) & 3) * 4 + (col & 3);
                o[i] = tile[d][key];
            }
            *(bf16x8*)(dst + swz8(qc)) = o;
        }
    }
}

// Flash attention, 32 q-rows/wave with ALL r6 confounds removed:
// - 128-row Q tile (4 waves x 32 rows): every K/V LDS read serves 2x the
//   q-rows -> wave-keytile encounters 8320->4224, LDS reads 532->270 MB,
//   staging + barrier count halved (the r6 mechanism).
// - KEY SPLIT STAYS 8-WAY -> opart/combine identical to the proven r4
//   version (no extra HBM traffic, 8-plane combine).
// - r7's pack-immediately softmax (exp -> bf16 words in place, sa/sb die
//   early) -> fits the 128-VGPR cap of __launch_bounds__(256,4), no spill.
// - r4's double-buffered global->LDS staging (32 KB LDS, 4 blocks/CU).
// Grid 1024 = T(32, bid-major) x qr(8) x batch(4); each CU's 4 blocks have
// T spread by 8 -> balanced; empty blocks (TK < qr) return immediately.
__global__ __launch_bounds__(256, 4) void fa_kernel(const float* __restrict__ q,
                                                    const __bf16* __restrict__ kbs,
                                                    const __bf16* __restrict__ vts,
                                                    __bf16* __restrict__ opart,
                                                    float* __restrict__ lpart) {
    __shared__ __bf16 smem[2][8192];   // 32 KB: [ K: 0..4095 | V: 4096..8191 ]

    const int tid  = threadIdx.x;
    const int wave = tid >> 6;
    const int lane = tid & 63;
    const int c    = lane & 15;
    const int quad = lane >> 4;
    const int bid   = blockIdx.x;        // T*32 + qr*4 + batch
    const int batch = bid & 3;
    const int qr    = (bid >> 2) & 7;    // key-eighth 0..7
    const int T     = bid >> 5;          // 128-row Q tile 0..31
    const int TK    = 2 * T + 1;         // highest valid 64-key tile

    const int n = (TK >= qr) ? ((TK - qr) >> 3) + 1 : 0;
    if (n == 0) return;                  // empty block

    const float sc = 0.125f * 1.4426950408889634f;
    const long offB = (long)batch * SD * DH;

    const int sw   = c & 7;
    const int off0 = ((quad ^ sw) << 3);
    const int off1 = (((quad + 4) ^ sw) << 3);
    const int rowc = c * 64;

    const int myq = T * 128 + wave * 32;   // this wave's 32 q rows

    // staging: wave w fills LDS bytes [w*4096, w*4096+4096) of the buffer;
    // waves 0,1 copy the K tile image, waves 2,3 the V tile image.
    const long tileB = (long)batch * 64;
    auto stage = [&](int kt, int bufi) {
        const char* gsrc = (wave < 2)
            ? (const char*)(kbs + (tileB + kt) * 4096) + wave * 4096
            : (const char*)(vts + (tileB + kt) * 4096) + (wave - 2) * 4096;
        char* ldst = (char*)(&smem[bufi][0]) + wave * 4096;
#pragma unroll
        for (int i = 0; i < 4; ++i)
            load_lds16(gsrc + i * 1024 + lane * 16, ldst + i * 1024);
    };

    // prime buffer 0 first (DMA starts before Q loads issue)
    stage(qr, 0);

    // ---- Q fragments (B operand) for both 16-row groups, pre-scaled ----
    bf16x8 qf0, qf1, qf2, qf3;
    {
        const float* qp0 = q + offB + (long)(myq + c) * DH + quad * 8;
        const float* qp1 = qp0 + 16 * DH;
        float4 a0 = *(const float4*)(qp0);
        float4 a1 = *(const float4*)(qp0 + 4);
        float4 a2 = *(const float4*)(qp0 + 32);
        float4 a3 = *(const float4*)(qp0 + 36);
        float4 b0 = *(const float4*)(qp1);
        float4 b1 = *(const float4*)(qp1 + 4);
        float4 b2 = *(const float4*)(qp1 + 32);
        float4 b3 = *(const float4*)(qp1 + 36);
        qf0[0]=(__bf16)(a0.x*sc); qf0[1]=(__bf16)(a0.y*sc); qf0[2]=(__bf16)(a0.z*sc); qf0[3]=(__bf16)(a0.w*sc);
        qf0[4]=(__bf16)(a1.x*sc); qf0[5]=(__bf16)(a1.y*sc); qf0[6]=(__bf16)(a1.z*sc); qf0[7]=(__bf16)(a1.w*sc);
        qf1[0]=(__bf16)(a2.x*sc); qf1[1]=(__bf16)(a2.y*sc); qf1[2]=(__bf16)(a2.z*sc); qf1[3]=(__bf16)(a2.w*sc);
        qf1[4]=(__bf16)(a3.x*sc); qf1[5]=(__bf16)(a3.y*sc); qf1[6]=(__bf16)(a3.z*sc); qf1[7]=(__bf16)(a3.w*sc);
        qf2[0]=(__bf16)(b0.x*sc); qf2[1]=(__bf16)(b0.y*sc); qf2[2]=(__bf16)(b0.z*sc); qf2[3]=(__bf16)(b0.w*sc);
        qf2[4]=(__bf16)(b1.x*sc); qf2[5]=(__bf16)(b1.y*sc); qf2[6]=(__bf16)(b1.z*sc); qf2[7]=(__bf16)(b1.w*sc);
        qf3[0]=(__bf16)(b2.x*sc); qf3[1]=(__bf16)(b2.y*sc); qf3[2]=(__bf16)(b2.z*sc); qf3[3]=(__bf16)(b2.w*sc);
        qf3[4]=(__bf16)(b3.x*sc); qf3[5]=(__bf16)(b3.y*sc); qf3[6]=(__bf16)(b3.z*sc); qf3[7]=(__bf16)(b3.w*sc);
    }

    floatx4 o0 = {0.f,0.f,0.f,0.f}, o1 = o0, o2 = o0, o3 = o0;
    floatx4 o4 = o0, o5 = o0, o6 = o0, o7 = o0;
    float l0 = 0.0f, l1 = 0.0f;

#pragma unroll 1
    for (int j = 0; j < n; ++j) {
        const int kt = qr + 8 * j;
        // wait current tile's 4 loads (+ Q loads at j=0) + all waves
        sync_all();
        // issue next tile's loads AFTER the barrier (race-free dbuf);
        // they fly across the whole compute body below.
        if (j + 1 < n) stage(kt + 8, (j + 1) & 1);

        const int kbase = kt * 64;
        if (kbase > myq + 31) continue;   // fully masked for this wave

        const __bf16* kbuf = &smem[j & 1][0];
        const __bf16* vbuf = kbuf + 4096;
        floatx4 sa[4], sb[4];
        __builtin_amdgcn_s_setprio(1);
#pragma unroll
        for (int t = 0; t < 4; ++t) {
            bf16x8 ka  = *(const bf16x8*)(kbuf + t * 1024 + rowc + off0);
            bf16x8 kb2 = *(const bf16x8*)(kbuf + t * 1024 + rowc + off1);
            floatx4 a = {0.f,0.f,0.f,0.f};
            floatx4 b = {0.f,0.f,0.f,0.f};
            a = __builtin_amdgcn_mfma_f32_16x16x32_bf16(ka,  qf0, a, 0, 0, 0);
            a = __builtin_amdgcn_mfma_f32_16x16x32_bf16(kb2, qf1, a, 0, 0, 0);
            b = __builtin_amdgcn_mfma_f32_16x16x32_bf16(ka,  qf2, b, 0, 0, 0);
            b = __builtin_amdgcn_mfma_f32_16x16x32_bf16(kb2, qf3, b, 0, 0, 0);
            sa[t] = a; sb[t] = b;
        }
        __builtin_amdgcn_s_setprio(0);

        // ---- softmax: exp + mask, ACCUMULATE l, pack to bf16 words
        //      immediately (sa/sb die here; only 16 u32 stay live) ----
        unsigned bpw[8], bqw[8];
        {
            const int qrow0 = myq + c;
            if (kbase + 63 > myq) {   // diagonal region for group 0
#pragma unroll
                for (int t = 0; t < 4; ++t) {
                    float e0,e1,e2,e3;
                    int k0 = kbase + t*16 + quad*4;
                    e0 = (k0     <= qrow0) ? exp2fast(sa[t][0]) : 0.0f;
                    e1 = (k0 + 1 <= qrow0) ? exp2fast(sa[t][1]) : 0.0f;
                    e2 = (k0 + 2 <= qrow0) ? exp2fast(sa[t][2]) : 0.0f;
                    e3 = (k0 + 3 <= qrow0) ? exp2fast(sa[t][3]) : 0.0f;
                    l0 += (e0 + e2) + (e1 + e3);
                    bpw[2*t]   = pack_bf16_2(e0, e1);
                    bpw[2*t+1] = pack_bf16_2(e2, e3);
                }
            } else {
#pragma unroll
                for (int t = 0; t < 4; ++t) {
                    float e0 = exp2fast(sa[t][0]);
                    float e1 = exp2fast(sa[t][1]);
                    float e2 = exp2fast(sa[t][2]);
                    float e3 = exp2fast(sa[t][3]);
                    l0 += (e0 + e2) + (e1 + e3);
                    bpw[2*t]   = pack_bf16_2(e0, e1);
                    bpw[2*t+1] = pack_bf16_2(e2, e3);
                }
            }
            const int qrow1 = myq + 16 + c;
            if (kbase + 63 > myq + 16) {   // diagonal region for group 1
#pragma unroll
                for (int t = 0; t < 4; ++t) {
                    float e0,e1,e2,e3;
                    int k0 = kbase + t*16 + quad*4;
                    e0 = (k0     <= qrow1) ? exp2fast(sb[t][0]) : 0.0f;
                    e1 = (k0 + 1 <= qrow1) ? exp2fast(sb[t][1]) : 0.0f;
                    e2 = (k0 + 2 <= qrow1) ? exp2fast(sb[t][2]) : 0.0f;
                    e3 = (k0 + 3 <= qrow1) ? exp2fast(sb[t][3]) : 0.0f;
                    l1 += (e0 + e2) + (e1 + e3);
                    bqw[2*t]   = pack_bf16_2(e0, e1);
                    bqw[2*t+1] = pack_bf16_2(e2, e3);
                }
            } else {
#pragma unroll
                for (int t = 0; t < 4; ++t) {
                    float e0 = exp2fast(sb[t][0]);
                    float e1 = exp2fast(sb[t][1]);
                    float e2 = exp2fast(sb[t][2]);
                    float e3 = exp2fast(sb[t][3]);
                    l1 += (e0 + e2) + (e1 + e3);
                    bqw[2*t]   = pack_bf16_2(e0, e1);
                    bqw[2*t+1] = pack_bf16_2(e2, e3);
                }
            }
        }

        __builtin_amdgcn_s_setprio(1);
#pragma unroll
        for (int s = 0; s < 2; ++s) {
            union { unsigned u[4]; bf16x8 f; } bp, bq;
            bp.u[0] = bpw[4*s+0]; bp.u[1] = bpw[4*s+1];
            bp.u[2] = bpw[4*s+2]; bp.u[3] = bpw[4*s+3];
            bq.u[0] = bqw[4*s+0]; bq.u[1] = bqw[4*s+1];
            bq.u[2] = bqw[4*s+2]; bq.u[3] = bqw[4*s+3];
            const int offs = s ? off1 : off0;
            bf16x8 v0 = *(const bf16x8*)(vbuf + 0*1024 + rowc + offs);
            bf16x8 v1 = *(const bf16x8*)(vbuf + 1*1024 + rowc + offs);
            bf16x8 v2 = *(const bf16x8*)(vbuf + 2*1024 + rowc + offs);
            bf16x8 v3 = *(const bf16x8*)(vbuf + 3*1024 + rowc + offs);
            o0 = __builtin_amdgcn_mfma_f32_16x16x32_bf16(v0, bp.f, o0, 0, 0, 0);
            o1 = __builtin_amdgcn_mfma_f32_16x16x32_bf16(v1, bp.f, o1, 0, 0, 0);
            o2 = __builtin_amdgcn_mfma_f32_16x16x32_bf16(v2, bp.f, o2, 0, 0, 0);
            o3 = __builtin_amdgcn_mfma_f32_16x16x32_bf16(v3, bp.f, o3, 0, 0, 0);
            o4 = __builtin_amdgcn_mfma_f32_16x16x32_bf16(v0, bq.f, o4, 0, 0, 0);
            o5 = __builtin_amdgcn_mfma_f32_16x16x32_bf16(v1, bq.f, o5, 0, 0, 0);
            o6 = __builtin_amdgcn_mfma_f32_16x16x32_bf16(v2, bq.f, o6, 0, 0, 0);
            o7 = __builtin_amdgcn_mfma_f32_16x16x32_bf16(v3, bq.f, o7, 0, 0, 0);
        }
        __builtin_amdgcn_s_setprio(0);
    }

    l0 += __shfl_xor(l0, 16);
    l0 += __shfl_xor(l0, 32);
    l1 += __shfl_xor(l1, 16);
    l1 += __shfl_xor(l1, 32);

    // ---- partial stores (bf16); combine reads plane qr for 64-row tile
    // t64 iff qr <= min(t64,7); this block wrote all such rows (TK>=qr) ----
    {
        __bf16* ob = opart + ((long)qr * NB + batch) * (long)(SD * DH) + (long)myq * DH;
        floatx4 ov[4] = {o0, o1, o2, o3};
#pragma unroll
        for (int dt = 0; dt < 4; ++dt) {
            uint2 sO;
            sO.x = pack_bf16_2(ov[dt][0], ov[dt][1]);
            sO.y = pack_bf16_2(ov[dt][2], ov[dt][3]);
            *(uint2*)(ob + c * DH + dt*16 + quad*4) = sO;
        }
        floatx4 ow[4] = {o4, o5, o6, o7};
#pragma unroll
        for (int dt = 0; dt < 4; ++dt) {
            uint2 sO;
            sO.x = pack_bf16_2(ow[dt][0], ow[dt][1]);
            sO.y = pack_bf16_2(ow[dt][2], ow[dt][3]);
            *(uint2*)(ob + (16 + c) * DH + dt*16 + quad*4) = sO;
        }
        if (quad == 0) {
            lpart[((long)qr * NB + batch) * SD + myq + c]      = l0;
            lpart[((long)qr * NB + batch) * SD + myq + 16 + c] = l1;
        }
    }
}

// out = (sum of valid key-eighth bf16 O partials) / (sum of l partials)
// 8 outputs per thread, bf16x8 (16B) partial reads -> 512 blocks.
__global__ __launch_bounds__(256) void combine_kernel(const __bf16* __restrict__ opart,
                                                      const float* __restrict__ lpart,
                                                      float* __restrict__ out) {
    const long t     = (long)blockIdx.x * 256 + threadIdx.x;  // 0..131071
    const long base8 = t * 8;                                 // element index
    const long qq    = base8 >> 6;                            // b*SD + q
    const int  T     = ((int)(qq & (SD - 1))) >> 6;           // 64-row tile of row
    const int  nqr   = (T < 7 ? T : 7) + 1;                   // populated planes
    float a0=0.f,a1=0.f,a2=0.f,a3=0.f,a4=0.f,a5=0.f,a6=0.f,a7=0.f, den=0.f;
    for (int qr = 0; qr < nqr; ++qr) {
        bf16x8 p = *(const bf16x8*)(opart + ((long)qr << 20) + base8);
        a0 += (float)p[0]; a1 += (float)p[1]; a2 += (float)p[2]; a3 += (float)p[3];
        a4 += (float)p[4]; a5 += (float)p[5]; a6 += (float)p[6]; a7 += (float)p[7];
        den += lpart[((long)qr << 14) + qq];
    }
    const float inv = 1.0f / den;
    float4 o0, o1;
    o0.x = a0*inv; o0.y = a1*inv; o0.z = a2*inv; o0.w = a3*inv;
    o1.x = a4*inv; o1.y = a5*inv; o1.z = a6*inv; o1.w = a7*inv;
    *(float4*)(out + base8)     = o0;
    *(float4*)(out + base8 + 4) = o1;
}

extern "C" void kernel_launch(void* const* d_in, const int* in_sizes, int n_in,
                              void* d_out, int out_size, void* d_ws, size_t ws_size,
                              hipStream_t stream) {
    const float* q = (const float*)d_in[0];
    const float* k = (const float*)d_in[1];
    const float* v = (const float*)d_in[2];
    float* out = (float*)d_out;
    __bf16* kbs   = (__bf16*)d_ws;                                 // 2MB (256 tiles x 8KB)
    __bf16* vts   = (__bf16*)((char*)d_ws + (2u << 20));           // 2MB
    __bf16* opart = (__bf16*)((char*)d_ws + (4u << 20));           // 16MB (8 splits)
    float*  lpart = (float*)((char*)d_ws + (20u << 20));           // 512KB
    prep_kernel<<<dim3(256), dim3(256), 0, stream>>>(k, v, kbs, vts);
    fa_kernel<<<dim3(1024), dim3(256), 0, stream>>>(q, kbs, vts, opart, lpart);
    combine_kernel<<<dim3(512), dim3(256), 0, stream>>>(opart, lpart, out);
}

// Round 10
// 90.663 us; speedup vs baseline: 1.0070x; 1.0070x over previous
//
#include <hip/hip_runtime.h>
#include <hip/hip_bf16.h>

typedef __bf16 bf16x8 __attribute__((ext_vector_type(8)));
typedef __bf16 bf16x4 __attribute__((ext_vector_type(4)));
typedef float  floatx4 __attribute__((ext_vector_type(4)));

#define SD 4096
#define DH 64
#define NB 4

__device__ __forceinline__ float exp2fast(float x) { return __builtin_amdgcn_exp2f(x); }

__device__ __forceinline__ unsigned pack_bf16_2(float a, float b) {
    union { __bf16 h[2]; unsigned u; } cvt;
    cvt.h[0] = (__bf16)a; cvt.h[1] = (__bf16)b;
    return cvt.u;
}

// Full drain + barrier (raw; compiler doesn't add extra waits around it).
__device__ __forceinline__ void sync_all() {
    asm volatile("s_waitcnt vmcnt(0) lgkmcnt(0)\n\ts_barrier" ::: "memory");
}

// Direct global->LDS DMA, 16 B per lane. LDS dest must be wave-uniform;
// HW writes dest + lane*16.
__device__ __forceinline__ void load_lds16(const void* g, void* l) {
    __builtin_amdgcn_global_load_lds(
        (const __attribute__((address_space(1))) unsigned int*)g,
        (__attribute__((address_space(3))) unsigned int*)l, 16, 0, 0);
}

// chunk index g (16B units within an 8KB tile) -> swizzled element offset
__device__ __forceinline__ int swz8(int g) {
    int row = g >> 3, ch = g & 7;
    return row * 64 + ((ch ^ (row & 7)) << 3);
}

// Pre-pass: build per-64-key-tile LDS images (8 KB each, XOR-swizzled chunk
// order) for K (bf16 natural rows) and V (transposed + column-PERMUTED so
// P^T exits QK^T already in B-operand order).
__global__ __launch_bounds__(256) void prep_kernel(const float* __restrict__ k,
                                                   const float* __restrict__ v,
                                                   __bf16* __restrict__ kbs,
                                                   __bf16* __restrict__ vts) {
    __shared__ __bf16 tile[64][72];   // [d][key]
    const int bid = blockIdx.x;       // b*64 + kt
    const int tid = threadIdx.x;
    const long base = (long)bid * 4096;   // element offset of 64x64 fp32 tile

    // ---- K: convert + swizzled chunk write (no LDS round-trip) ----
    {
        const float* src = k + base + tid * 16;   // = row(t>>2)*64 + (t&3)*16
        float4 f0 = *(const float4*)(src);
        float4 f1 = *(const float4*)(src + 4);
        float4 f2 = *(const float4*)(src + 8);
        float4 f3 = *(const float4*)(src + 12);
        bf16x8 c0, c1;
        c0[0]=(__bf16)f0.x; c0[1]=(__bf16)f0.y; c0[2]=(__bf16)f0.z; c0[3]=(__bf16)f0.w;
        c0[4]=(__bf16)f1.x; c0[5]=(__bf16)f1.y; c0[6]=(__bf16)f1.z; c0[7]=(__bf16)f1.w;
        c1[0]=(__bf16)f2.x; c1[1]=(__bf16)f2.y; c1[2]=(__bf16)f2.z; c1[3]=(__bf16)f2.w;
        c1[4]=(__bf16)f3.x; c1[5]=(__bf16)f3.y; c1[6]=(__bf16)f3.z; c1[7]=(__bf16)f3.w;
        __bf16* dst = kbs + base;   // 4096 bf16 elements per tile
        *(bf16x8*)(dst + swz8(tid * 2))     = c0;
        *(bf16x8*)(dst + swz8(tid * 2 + 1)) = c1;
    }
    // ---- V: load 64x64, transpose into tile[d][key] ----
    {
        int r = tid >> 2, ds0 = (tid & 3) * 16;
#pragma unroll
        for (int i = 0; i < 4; ++i) {
            float4 f = *(const float4*)(v + base + r * 64 + ds0 + i * 4);
            tile[ds0 + i*4 + 0][r] = (__bf16)f.x;
            tile[ds0 + i*4 + 1][r] = (__bf16)f.y;
            tile[ds0 + i*4 + 2][r] = (__bf16)f.z;
            tile[ds0 + i*4 + 3][r] = (__bf16)f.w;
        }
    }
    __syncthreads();
    // ---- V: permuted-column chunk write (swizzled positions) ----
    {
        __bf16* dst = vts + base;
#pragma unroll
        for (int h = 0; h < 2; ++h) {
            int qc = tid * 2 + h;
            int d = qc >> 3, c8 = (qc & 7) * 8;
            bf16x8 o;
#pragma unroll
            for (int i = 0; i < 8; ++i) {
                int col = c8 + i;
                int key = ((col >> 5) * 2 + ((col >> 2) & 1)) * 16
                        + ((col >> 3) & 3) * 4 + (col & 3);
                o[i] = tile[d][key];
            }
            *(bf16x8*)(dst + swz8(qc)) = o;
        }
    }
}

// Flash attention (proven r4 structure: 16 q-rows/wave, 64-row Q tile,
// phases {T, 63-T}, 8-way key split, double-buffered global->LDS staging,
// both-phase Q prefetch, setprio around MFMA clusters) + XCD-aware block
// clustering: the 32 pr-blocks sharing (qr,batch) read the IDENTICAL
// ~144 KB set of K/V tile images, so the bid decode is arranged so they
// share bid%8 (the XCD round-robin residue) -> each group stays on one
// XCD, its working set resident in that XCD's 4MB L2 (4 groups x ~144KB
// per XCD). Pure perf heuristic; correctness independent of the mapping.
__global__ __launch_bounds__(256, 4) void fa_kernel(const float* __restrict__ q,
                                                    const __bf16* __restrict__ kbs,
                                                    const __bf16* __restrict__ vts,
                                                    __bf16* __restrict__ opart,
                                                    float* __restrict__ lpart) {
    __shared__ __bf16 smem[2][8192];   // 32 KB: [ K: 0..4095 | V: 4096..8191 ]

    const int tid  = threadIdx.x;
    const int wave = tid >> 6;
    const int lane = tid & 63;
    const int c    = lane & 15;
    const int quad = lane >> 4;
    // ---- XCD-clustered decode: x = bid%8 picks the XCD; group
    //      g = (bid>>8)*8 + x in 0..31 carries (qr,batch); pr = (bid>>3)&31.
    const int bid   = blockIdx.x;
    const int x     = bid & 7;
    const int y     = bid >> 3;          // 0..127
    const int pr    = y & 31;            // pair index 0..31
    const int g     = ((y >> 5) << 3) | x;   // group 0..31
    const int qr    = g >> 2;            // key-eighth 0..7
    const int batch = g & 3;
    const float sc = 0.125f * 1.4426950408889634f;

    const long offB = (long)batch * SD * DH;

    const int sw   = c & 7;
    const int off0 = ((quad ^ sw) << 3);
    const int off1 = (((quad + 4) ^ sw) << 3);
    const int rowc = c * 64;

    // staging: wave w fills LDS bytes [w*4096, w*4096+4096) of the buffer;
    // waves 0,1 copy the K tile image, waves 2,3 the V tile image.
    const long tileB = (long)batch * 64;

    auto stage = [&](int kt, int bufi) {
        const char* gsrc = (wave < 2)
            ? (const char*)(kbs + (tileB + kt) * 4096) + wave * 4096
            : (const char*)(vts + (tileB + kt) * 4096) + (wave - 2) * 4096;
        char* ldst = (char*)(&smem[bufi][0]) + wave * 4096;
#pragma unroll
        for (int i = 0; i < 4; ++i)
            load_lds16(gsrc + i * 1024 + lane * 16, ldst + i * 1024);
    };

    // ---- Q fragments (B operand) for BOTH phases, pre-scaled ----
    bf16x8 qA0, qA1, qB0, qB1;
    {
        const int T0 = pr, T1 = 63 - pr;
        const float* qp0 = q + offB + (long)(T0 * 64 + wave * 16 + c) * DH + quad * 8;
        const float* qp1 = q + offB + (long)(T1 * 64 + wave * 16 + c) * DH + quad * 8;
        float4 a0 = *(const float4*)(qp0);
        float4 a1 = *(const float4*)(qp0 + 4);
        float4 a2 = *(const float4*)(qp0 + 32);
        float4 a3 = *(const float4*)(qp0 + 36);
        float4 b0 = *(const float4*)(qp1);
        float4 b1 = *(const float4*)(qp1 + 4);
        float4 b2 = *(const float4*)(qp1 + 32);
        float4 b3 = *(const float4*)(qp1 + 36);
        qA0[0]=(__bf16)(a0.x*sc); qA0[1]=(__bf16)(a0.y*sc); qA0[2]=(__bf16)(a0.z*sc); qA0[3]=(__bf16)(a0.w*sc);
        qA0[4]=(__bf16)(a1.x*sc); qA0[5]=(__bf16)(a1.y*sc); qA0[6]=(__bf16)(a1.z*sc); qA0[7]=(__bf16)(a1.w*sc);
        qA1[0]=(__bf16)(a2.x*sc); qA1[1]=(__bf16)(a2.y*sc); qA1[2]=(__bf16)(a2.z*sc); qA1[3]=(__bf16)(a2.w*sc);
        qA1[4]=(__bf16)(a3.x*sc); qA1[5]=(__bf16)(a3.y*sc); qA1[6]=(__bf16)(a3.z*sc); qA1[7]=(__bf16)(a3.w*sc);
        qB0[0]=(__bf16)(b0.x*sc); qB0[1]=(__bf16)(b0.y*sc); qB0[2]=(__bf16)(b0.z*sc); qB0[3]=(__bf16)(b0.w*sc);
        qB0[4]=(__bf16)(b1.x*sc); qB0[5]=(__bf16)(b1.y*sc); qB0[6]=(__bf16)(b1.z*sc); qB0[7]=(__bf16)(b1.w*sc);
        qB1[0]=(__bf16)(b2.x*sc); qB1[1]=(__bf16)(b2.y*sc); qB1[2]=(__bf16)(b2.z*sc); qB1[3]=(__bf16)(b2.w*sc);
        qB1[4]=(__bf16)(b3.x*sc); qB1[5]=(__bf16)(b3.y*sc); qB1[6]=(__bf16)(b3.z*sc); qB1[7]=(__bf16)(b3.w*sc);
    }

#pragma unroll 1
    for (int ph = 0; ph < 2; ++ph) {
        const int T = ph ? 63 - pr : pr;      // 64-row Q tile index 0..63
        const int myq = T * 64 + wave * 16;   // this wave's 16 q rows
        const int qrow = myq + c;

        const bf16x8 qf0 = ph ? qB0 : qA0;
        const bf16x8 qf1 = ph ? qB1 : qA1;

        floatx4 o0 = {0.f,0.f,0.f,0.f}, o1 = o0, o2 = o0, o3 = o0;
        float l = 0.0f;

        const int n = (T >= qr) ? ((T - qr) >> 3) + 1 : 0;   // block-uniform

        // phase-top: drain everything (prior-phase stores/reads), then
        // prime buffer 0.
        sync_all();
        if (n > 0) stage(qr, 0);

#pragma unroll 1
        for (int j = 0; j < n; ++j) {
            const int kt = qr + 8 * j;
            // wait current tile's 4 loads (only thing in flight) + all waves
            sync_all();
            // issue next tile's loads AFTER the barrier (race-free dbuf);
            // they fly across the whole compute body below.
            if (j + 1 < n) stage(kt + 8, (j + 1) & 1);

            const int kbase = kt * 64;
            if (kbase > myq + 15) continue;   // fully masked for this wave

            const __bf16* kbuf = &smem[j & 1][0];
            const __bf16* vbuf = kbuf + 4096;
            floatx4 sa[4];
            __builtin_amdgcn_s_setprio(1);
#pragma unroll
            for (int t = 0; t < 4; ++t) {
                bf16x8 ka  = *(const bf16x8*)(kbuf + t * 1024 + rowc + off0);
                bf16x8 kb2 = *(const bf16x8*)(kbuf + t * 1024 + rowc + off1);
                floatx4 a = {0.f,0.f,0.f,0.f};
                a = __builtin_amdgcn_mfma_f32_16x16x32_bf16(ka,  qf0, a, 0, 0, 0);
                a = __builtin_amdgcn_mfma_f32_16x16x32_bf16(kb2, qf1, a, 0, 0, 0);
                sa[t] = a;
            }
            __builtin_amdgcn_s_setprio(0);
            float pe[16];
            if (kbase + 63 > myq) {   // diagonal region: causal mask
#pragma unroll
                for (int t = 0; t < 4; ++t)
#pragma unroll
                    for (int r = 0; r < 4; ++r) {
                        int key = kbase + t*16 + quad*4 + r;
                        pe[t*4+r] = (key <= qrow) ? exp2fast(sa[t][r]) : 0.0f;
                    }
            } else {
#pragma unroll
                for (int t = 0; t < 4; ++t)
#pragma unroll
                    for (int r = 0; r < 4; ++r) pe[t*4+r] = exp2fast(sa[t][r]);
            }
            {
                float s8[8], s4v[4];
#pragma unroll
                for (int i = 0; i < 8; ++i) s8[i] = pe[i] + pe[i+8];
#pragma unroll
                for (int i = 0; i < 4; ++i) s4v[i] = s8[i] + s8[i+4];
                l += (s4v[0] + s4v[2]) + (s4v[1] + s4v[3]);
            }
            __builtin_amdgcn_s_setprio(1);
#pragma unroll
            for (int s = 0; s < 2; ++s) {
                union { unsigned u[4]; bf16x8 f; } bp;
#pragma unroll
                for (int jj = 0; jj < 4; ++jj)
                    bp.u[jj] = pack_bf16_2(pe[8*s + 2*jj], pe[8*s + 2*jj + 1]);
                const int offs = s ? off1 : off0;
                bf16x8 v0 = *(const bf16x8*)(vbuf + 0*1024 + rowc + offs);
                bf16x8 v1 = *(const bf16x8*)(vbuf + 1*1024 + rowc + offs);
                bf16x8 v2 = *(const bf16x8*)(vbuf + 2*1024 + rowc + offs);
                bf16x8 v3 = *(const bf16x8*)(vbuf + 3*1024 + rowc + offs);
                o0 = __builtin_amdgcn_mfma_f32_16x16x32_bf16(v0, bp.f, o0, 0, 0, 0);
                o1 = __builtin_amdgcn_mfma_f32_16x16x32_bf16(v1, bp.f, o1, 0, 0, 0);
                o2 = __builtin_amdgcn_mfma_f32_16x16x32_bf16(v2, bp.f, o2, 0, 0, 0);
                o3 = __builtin_amdgcn_mfma_f32_16x16x32_bf16(v3, bp.f, o3, 0, 0, 0);
            }
            __builtin_amdgcn_s_setprio(0);
        }

        l += __shfl_xor(l, 16);
        l += __shfl_xor(l, 32);

        // ---- partial stores (bf16); skip when this eighth is empty
        // (combine only reads qr <= min(T,7) planes) ----
        if (n > 0) {
            __bf16* ob = opart + ((long)qr * NB + batch) * (long)(SD * DH) + (long)myq * DH;
            {
                floatx4 ov[4] = {o0, o1, o2, o3};
#pragma unroll
                for (int dt = 0; dt < 4; ++dt) {
                    uint2 sO;
                    sO.x = pack_bf16_2(ov[dt][0], ov[dt][1]);
                    sO.y = pack_bf16_2(ov[dt][2], ov[dt][3]);
                    *(uint2*)(ob + c * DH + dt*16 + quad*4) = sO;
                }
            }
            if (quad == 0)
                lpart[((long)qr * NB + batch) * SD + myq + c] = l;
        }
    }
}

// out = (sum of valid key-eighth bf16 O partials) / (sum of l partials)
// 8 outputs per thread, bf16x8 (16B) partial reads -> 512 blocks.
__global__ __launch_bounds__(256) void combine_kernel(const __bf16* __restrict__ opart,
                                                      const float* __restrict__ lpart,
                                                      float* __restrict__ out) {
    const long t     = (long)blockIdx.x * 256 + threadIdx.x;  // 0..131071
    const long base8 = t * 8;                                 // element index
    const long qq    = base8 >> 6;                            // b*SD + q
    const int  T     = ((int)(qq & (SD - 1))) >> 6;           // Q tile of row
    const int  nqr   = (T < 7 ? T : 7) + 1;                   // populated planes
    float a0=0.f,a1=0.f,a2=0.f,a3=0.f,a4=0.f,a5=0.f,a6=0.f,a7=0.f, den=0.f;
    for (int qr = 0; qr < nqr; ++qr) {
        bf16x8 p = *(const bf16x8*)(opart + ((long)qr << 20) + base8);
        a0 += (float)p[0]; a1 += (float)p[1]; a2 += (float)p[2]; a3 += (float)p[3];
        a4 += (float)p[4]; a5 += (float)p[5]; a6 += (float)p[6]; a7 += (float)p[7];
        den += lpart[((long)qr << 14) + qq];
    }
    const float inv = 1.0f / den;
    float4 o0, o1;
    o0.x = a0*inv; o0.y = a1*inv; o0.z = a2*inv; o0.w = a3*inv;
    o1.x = a4*inv; o1.y = a5*inv; o1.z = a6*inv; o1.w = a7*inv;
    *(float4*)(out + base8)     = o0;
    *(float4*)(out + base8 + 4) = o1;
}

extern "C" void kernel_launch(void* const* d_in, const int* in_sizes, int n_in,
                              void* d_out, int out_size, void* d_ws, size_t ws_size,
                              hipStream_t stream) {
    const float* q = (const float*)d_in[0];
    const float* k = (const float*)d_in[1];
    const float* v = (const float*)d_in[2];
    float* out = (float*)d_out;
    __bf16* kbs   = (__bf16*)d_ws;                                 // 2MB (256 tiles x 8KB)
    __bf16* vts   = (__bf16*)((char*)d_ws + (2u << 20));           // 2MB
    __bf16* opart = (__bf16*)((char*)d_ws + (4u << 20));           // 16MB (8 splits)
    float*  lpart = (float*)((char*)d_ws + (20u << 20));           // 512KB
    prep_kernel<<<dim3(256), dim3(256), 0, stream>>>(k, v, kbs, vts);
    fa_kernel<<<dim3(1024), dim3(256), 0, stream>>>(q, kbs, vts, opart, lpart);
    combine_kernel<<<dim3(512), dim3(256), 0, stream>>>(opart, lpart, out);
}

// Round 11
// 88.061 us; speedup vs baseline: 1.0367x; 1.0296x over previous
//
#include <hip/hip_runtime.h>
#include <hip/hip_bf16.h>

typedef __bf16 bf16x8 __attribute__((ext_vector_type(8)));
typedef __bf16 bf16x4 __attribute__((ext_vector_type(4)));
typedef float  floatx4 __attribute__((ext_vector_type(4)));

#define SD 4096
#define DH 64
#define NB 4

__device__ __forceinline__ float exp2fast(float x) { return __builtin_amdgcn_exp2f(x); }

__device__ __forceinline__ unsigned pack_bf16_2(float a, float b) {
    union { __bf16 h[2]; unsigned u; } cvt;
    cvt.h[0] = (__bf16)a; cvt.h[1] = (__bf16)b;
    return cvt.u;
}

// Full drain + barrier (raw; compiler doesn't add extra waits around it).
__device__ __forceinline__ void sync_all() {
    asm volatile("s_waitcnt vmcnt(0) lgkmcnt(0)\n\ts_barrier" ::: "memory");
}

// Direct global->LDS DMA, 16 B per lane. LDS dest must be wave-uniform;
// HW writes dest + lane*16.
__device__ __forceinline__ void load_lds16(const void* g, void* l) {
    __builtin_amdgcn_global_load_lds(
        (const __attribute__((address_space(1))) unsigned int*)g,
        (__attribute__((address_space(3))) unsigned int*)l, 16, 0, 0);
}

// chunk index g (16B units within an 8KB tile) -> swizzled element offset
__device__ __forceinline__ int swz8(int g) {
    int row = g >> 3, ch = g & 7;
    return row * 64 + ((ch ^ (row & 7)) << 3);
}

// Pre-pass: build per-64-key-tile LDS images (8 KB each, XOR-swizzled chunk
// order) for K (bf16 natural rows) and V (transposed + column-PERMUTED so
// P^T exits QK^T already in B-operand order).
__global__ __launch_bounds__(256) void prep_kernel(const float* __restrict__ k,
                                                   const float* __restrict__ v,
                                                   __bf16* __restrict__ kbs,
                                                   __bf16* __restrict__ vts) {
    __shared__ __bf16 tile[64][72];   // [d][key]
    const int bid = blockIdx.x;       // b*64 + kt
    const int tid = threadIdx.x;
    const long base = (long)bid * 4096;   // element offset of 64x64 fp32 tile

    // ---- K: convert + swizzled chunk write (no LDS round-trip) ----
    {
        const float* src = k + base + tid * 16;   // = row(t>>2)*64 + (t&3)*16
        float4 f0 = *(const float4*)(src);
        float4 f1 = *(const float4*)(src + 4);
        float4 f2 = *(const float4*)(src + 8);
        float4 f3 = *(const float4*)(src + 12);
        bf16x8 c0, c1;
        c0[0]=(__bf16)f0.x; c0[1]=(__bf16)f0.y; c0[2]=(__bf16)f0.z; c0[3]=(__bf16)f0.w;
        c0[4]=(__bf16)f1.x; c0[5]=(__bf16)f1.y; c0[6]=(__bf16)f1.z; c0[7]=(__bf16)f1.w;
        c1[0]=(__bf16)f2.x; c1[1]=(__bf16)f2.y; c1[2]=(__bf16)f2.z; c1[3]=(__bf16)f2.w;
        c1[4]=(__bf16)f3.x; c1[5]=(__bf16)f3.y; c1[6]=(__bf16)f3.z; c1[7]=(__bf16)f3.w;
        __bf16* dst = kbs + base;   // 4096 bf16 elements per tile
        *(bf16x8*)(dst + swz8(tid * 2))     = c0;
        *(bf16x8*)(dst + swz8(tid * 2 + 1)) = c1;
    }
    // ---- V: load 64x64, transpose into tile[d][key] ----
    {
        int r = tid >> 2, ds0 = (tid & 3) * 16;
#pragma unroll
        for (int i = 0; i < 4; ++i) {
            float4 f = *(const float4*)(v + base + r * 64 + ds0 + i * 4);
            tile[ds0 + i*4 + 0][r] = (__bf16)f.x;
            tile[ds0 + i*4 + 1][r] = (__bf16)f.y;
            tile[ds0 + i*4 + 2][r] = (__bf16)f.z;
            tile[ds0 + i*4 + 3][r] = (__bf16)f.w;
        }
    }
    __syncthreads();
    // ---- V: permuted-column chunk write (swizzled positions) ----
    {
        __bf16* dst = vts + base;
#pragma unroll
        for (int h = 0; h < 2; ++h) {
            int qc = tid * 2 + h;
            int d = qc >> 3, c8 = (qc & 7) * 8;
            bf16x8 o;
#pragma unroll
            for (int i = 0; i < 8; ++i) {
                int col = c8 + i;
                int key = ((col >> 5) * 2 + ((col >> 2) & 1)) * 16
                        + ((col >> 3) & 3) * 4 + (col & 3);
                o[i] = tile[d][key];
            }
            *(bf16x8*)(dst + swz8(qc)) = o;
        }
    }
}

// Flash attention: double-buffered direct global->LDS staging. Block = 256
// thr / 4 waves = 64-row Q tile; phases {T, 63-T}; keys split 8-way across
// blocks -> 1024 blocks, 4/CU. Q fragments for BOTH phases are loaded and
// converted up front (hides phase-1's Q HBM latency under phase 0).
// s_setprio(1) wraps the MFMA clusters: with 4 independent blocks/CU the
// waves on a SIMD sit at different phases, so priority arbitration pays
// (attn-positive regime, m191).
__global__ __launch_bounds__(256, 4) void fa_kernel(const float* __restrict__ q,
                                                    const __bf16* __restrict__ kbs,
                                                    const __bf16* __restrict__ vts,
                                                    __bf16* __restrict__ opart,
                                                    float* __restrict__ lpart) {
    __shared__ __bf16 smem[2][8192];   // 32 KB: [ K: 0..4095 | V: 4096..8191 ]

    const int tid  = threadIdx.x;
    const int wave = tid >> 6;
    const int lane = tid & 63;
    const int c    = lane & 15;
    const int quad = lane >> 4;
    const int bid   = blockIdx.x;
    const int batch = bid & 3;
    const int pr    = (bid >> 2) & 31;   // pair index 0..31
    const int qr    = bid >> 7;          // key-eighth 0..7
    const float sc = 0.125f * 1.4426950408889634f;

    const long offB = (long)batch * SD * DH;

    const int sw   = c & 7;
    const int off0 = ((quad ^ sw) << 3);
    const int off1 = (((quad + 4) ^ sw) << 3);
    const int rowc = c * 64;

    // staging: wave w fills LDS bytes [w*4096, w*4096+4096) of the buffer;
    // waves 0,1 copy the K tile image, waves 2,3 the V tile image.
    const long tileB = (long)batch * 64;

    auto stage = [&](int kt, int bufi) {
        const char* gsrc = (wave < 2)
            ? (const char*)(kbs + (tileB + kt) * 4096) + wave * 4096
            : (const char*)(vts + (tileB + kt) * 4096) + (wave - 2) * 4096;
        char* ldst = (char*)(&smem[bufi][0]) + wave * 4096;
#pragma unroll
        for (int i = 0; i < 4; ++i)
            load_lds16(gsrc + i * 1024 + lane * 16, ldst + i * 1024);
    };

    // ---- Q fragments (B operand) for BOTH phases, pre-scaled ----
    bf16x8 qA0, qA1, qB0, qB1;
    {
        const int T0 = pr, T1 = 63 - pr;
        const float* qp0 = q + offB + (long)(T0 * 64 + wave * 16 + c) * DH + quad * 8;
        const float* qp1 = q + offB + (long)(T1 * 64 + wave * 16 + c) * DH + quad * 8;
        float4 a0 = *(const float4*)(qp0);
        float4 a1 = *(const float4*)(qp0 + 4);
        float4 a2 = *(const float4*)(qp0 + 32);
        float4 a3 = *(const float4*)(qp0 + 36);
        float4 b0 = *(const float4*)(qp1);
        float4 b1 = *(const float4*)(qp1 + 4);
        float4 b2 = *(const float4*)(qp1 + 32);
        float4 b3 = *(const float4*)(qp1 + 36);
        qA0[0]=(__bf16)(a0.x*sc); qA0[1]=(__bf16)(a0.y*sc); qA0[2]=(__bf16)(a0.z*sc); qA0[3]=(__bf16)(a0.w*sc);
        qA0[4]=(__bf16)(a1.x*sc); qA0[5]=(__bf16)(a1.y*sc); qA0[6]=(__bf16)(a1.z*sc); qA0[7]=(__bf16)(a1.w*sc);
        qA1[0]=(__bf16)(a2.x*sc); qA1[1]=(__bf16)(a2.y*sc); qA1[2]=(__bf16)(a2.z*sc); qA1[3]=(__bf16)(a2.w*sc);
        qA1[4]=(__bf16)(a3.x*sc); qA1[5]=(__bf16)(a3.y*sc); qA1[6]=(__bf16)(a3.z*sc); qA1[7]=(__bf16)(a3.w*sc);
        qB0[0]=(__bf16)(b0.x*sc); qB0[1]=(__bf16)(b0.y*sc); qB0[2]=(__bf16)(b0.z*sc); qB0[3]=(__bf16)(b0.w*sc);
        qB0[4]=(__bf16)(b1.x*sc); qB0[5]=(__bf16)(b1.y*sc); qB0[6]=(__bf16)(b1.z*sc); qB0[7]=(__bf16)(b1.w*sc);
        qB1[0]=(__bf16)(b2.x*sc); qB1[1]=(__bf16)(b2.y*sc); qB1[2]=(__bf16)(b2.z*sc); qB1[3]=(__bf16)(b2.w*sc);
        qB1[4]=(__bf16)(b3.x*sc); qB1[5]=(__bf16)(b3.y*sc); qB1[6]=(__bf16)(b3.z*sc); qB1[7]=(__bf16)(b3.w*sc);
    }

#pragma unroll 1
    for (int ph = 0; ph < 2; ++ph) {
        const int T = ph ? 63 - pr : pr;      // 64-row Q tile index 0..63
        const int myq = T * 64 + wave * 16;   // this wave's 16 q rows
        const int qrow = myq + c;

        const bf16x8 qf0 = ph ? qB0 : qA0;
        const bf16x8 qf1 = ph ? qB1 : qA1;

        floatx4 o0 = {0.f,0.f,0.f,0.f}, o1 = o0, o2 = o0, o3 = o0;
        float l = 0.0f;

        const int n = (T >= qr) ? ((T - qr) >> 3) + 1 : 0;   // block-uniform

        // phase-top: drain everything (prior-phase stores/reads), then
        // prime buffer 0.
        sync_all();
        if (n > 0) stage(qr, 0);

#pragma unroll 1
        for (int j = 0; j < n; ++j) {
            const int kt = qr + 8 * j;
            // wait current tile's 4 loads (only thing in flight) + all waves
            sync_all();
            // issue next tile's loads AFTER the barrier (race-free dbuf);
            // they fly across the whole compute body below.
            if (j + 1 < n) stage(kt + 8, (j + 1) & 1);

            const int kbase = kt * 64;
            if (kbase > myq + 15) continue;   // fully masked for this wave

            const __bf16* kbuf = &smem[j & 1][0];
            const __bf16* vbuf = kbuf + 4096;
            floatx4 sa[4];
            __builtin_amdgcn_s_setprio(1);
#pragma unroll
            for (int t = 0; t < 4; ++t) {
                bf16x8 ka  = *(const bf16x8*)(kbuf + t * 1024 + rowc + off0);
                bf16x8 kb2 = *(const bf16x8*)(kbuf + t * 1024 + rowc + off1);
                floatx4 a = {0.f,0.f,0.f,0.f};
                a = __builtin_amdgcn_mfma_f32_16x16x32_bf16(ka,  qf0, a, 0, 0, 0);
                a = __builtin_amdgcn_mfma_f32_16x16x32_bf16(kb2, qf1, a, 0, 0, 0);
                sa[t] = a;
            }
            __builtin_amdgcn_s_setprio(0);
            float pe[16];
            if (kbase + 63 > myq) {   // diagonal region: causal mask
#pragma unroll
                for (int t = 0; t < 4; ++t)
#pragma unroll
                    for (int r = 0; r < 4; ++r) {
                        int key = kbase + t*16 + quad*4 + r;
                        pe[t*4+r] = (key <= qrow) ? exp2fast(sa[t][r]) : 0.0f;
                    }
            } else {
#pragma unroll
                for (int t = 0; t < 4; ++t)
#pragma unroll
                    for (int r = 0; r < 4; ++r) pe[t*4+r] = exp2fast(sa[t][r]);
            }
            {
                float s8[8], s4v[4];
#pragma unroll
                for (int i = 0; i < 8; ++i) s8[i] = pe[i] + pe[i+8];
#pragma unroll
                for (int i = 0; i < 4; ++i) s4v[i] = s8[i] + s8[i+4];
                l += (s4v[0] + s4v[2]) + (s4v[1] + s4v[3]);
            }
            __builtin_amdgcn_s_setprio(1);
#pragma unroll
            for (int s = 0; s < 2; ++s) {
                union { unsigned u[4]; bf16x8 f; } bp;
#pragma unroll
                for (int jj = 0; jj < 4; ++jj)
                    bp.u[jj] = pack_bf16_2(pe[8*s + 2*jj], pe[8*s + 2*jj + 1]);
                const int offs = s ? off1 : off0;
                bf16x8 v0 = *(const bf16x8*)(vbuf + 0*1024 + rowc + offs);
                bf16x8 v1 = *(const bf16x8*)(vbuf + 1*1024 + rowc + offs);
                bf16x8 v2 = *(const bf16x8*)(vbuf + 2*1024 + rowc + offs);
                bf16x8 v3 = *(const bf16x8*)(vbuf + 3*1024 + rowc + offs);
                o0 = __builtin_amdgcn_mfma_f32_16x16x32_bf16(v0, bp.f, o0, 0, 0, 0);
                o1 = __builtin_amdgcn_mfma_f32_16x16x32_bf16(v1, bp.f, o1, 0, 0, 0);
                o2 = __builtin_amdgcn_mfma_f32_16x16x32_bf16(v2, bp.f, o2, 0, 0, 0);
                o3 = __builtin_amdgcn_mfma_f32_16x16x32_bf16(v3, bp.f, o3, 0, 0, 0);
            }
            __builtin_amdgcn_s_setprio(0);
        }

        l += __shfl_xor(l, 16);
        l += __shfl_xor(l, 32);

        // ---- partial stores (bf16); skip when this eighth is empty
        // (combine only reads qr <= min(T,7) planes) ----
        if (n > 0) {
            __bf16* ob = opart + ((long)qr * NB + batch) * (long)(SD * DH) + (long)myq * DH;
            {
                floatx4 ov[4] = {o0, o1, o2, o3};
#pragma unroll
                for (int dt = 0; dt < 4; ++dt) {
                    uint2 sO;
                    sO.x = pack_bf16_2(ov[dt][0], ov[dt][1]);
                    sO.y = pack_bf16_2(ov[dt][2], ov[dt][3]);
                    *(uint2*)(ob + c * DH + dt*16 + quad*4) = sO;
                }
            }
            if (quad == 0)
                lpart[((long)qr * NB + batch) * SD + myq + c] = l;
        }
    }
}

// out = (sum of valid key-eighth bf16 O partials) / (sum of l partials)
// 8 outputs per thread, bf16x8 (16B) partial reads -> 512 blocks.
__global__ __launch_bounds__(256) void combine_kernel(const __bf16* __restrict__ opart,
                                                      const float* __restrict__ lpart,
                                                      float* __restrict__ out) {
    const long t     = (long)blockIdx.x * 256 + threadIdx.x;  // 0..131071
    const long base8 = t * 8;                                 // element index
    const long qq    = base8 >> 6;                            // b*SD + q
    const int  T     = ((int)(qq & (SD - 1))) >> 6;           // Q tile of row
    const int  nqr   = (T < 7 ? T : 7) + 1;                   // populated planes
    float a0=0.f,a1=0.f,a2=0.f,a3=0.f,a4=0.f,a5=0.f,a6=0.f,a7=0.f, den=0.f;
    for (int qr = 0; qr < nqr; ++qr) {
        bf16x8 p = *(const bf16x8*)(opart + ((long)qr << 20) + base8);
        a0 += (float)p[0]; a1 += (float)p[1]; a2 += (float)p[2]; a3 += (float)p[3];
        a4 += (float)p[4]; a5 += (float)p[5]; a6 += (float)p[6]; a7 += (float)p[7];
        den += lpart[((long)qr << 14) + qq];
    }
    const float inv = 1.0f / den;
    float4 o0, o1;
    o0.x = a0*inv; o0.y = a1*inv; o0.z = a2*inv; o0.w = a3*inv;
    o1.x = a4*inv; o1.y = a5*inv; o1.z = a6*inv; o1.w = a7*inv;
    *(float4*)(out + base8)     = o0;
    *(float4*)(out + base8 + 4) = o1;
}

extern "C" void kernel_launch(void* const* d_in, const int* in_sizes, int n_in,
                              void* d_out, int out_size, void* d_ws, size_t ws_size,
                              hipStream_t stream) {
    const float* q = (const float*)d_in[0];
    const float* k = (const float*)d_in[1];
    const float* v = (const float*)d_in[2];
    float* out = (float*)d_out;
    __bf16* kbs   = (__bf16*)d_ws;                                 // 2MB (256 tiles x 8KB)
    __bf16* vts   = (__bf16*)((char*)d_ws + (2u << 20));           // 2MB
    __bf16* opart = (__bf16*)((char*)d_ws + (4u << 20));           // 16MB (8 splits)
    float*  lpart = (float*)((char*)d_ws + (20u << 20));           // 512KB
    prep_kernel<<<dim3(256), dim3(256), 0, stream>>>(k, v, kbs, vts);
    fa_kernel<<<dim3(1024), dim3(256), 0, stream>>>(q, kbs, vts, opart, lpart);
    combine_kernel<<<dim3(512), dim3(256), 0, stream>>>(opart, lpart, out);
}